// Round 17
// baseline (72.914 us; speedup 1.0000x reference)
//
#include <hip/hip_runtime.h>
#include <math.h>

// Problem constants
#define BATCH 4096
#define NFEAT 2048
#define NNEUR 1024
#define NTGT  8
#define NNZ1  65536
#define NNZ2  8192

// out[n][t] = b2[t] + sum_m sigmoid(sum_k W1[m][k]x[n][k] + b1[m]) * W2[m][t]
// VMEM-minimized GEMM (R16 post-mortem: every design sits at ~15-20 B/cyc/CU
// VMEM delivery; minimize requested bytes): 128x128 block (grid 256, full CU
// coverage), BOTH operands bf16 pre-converted, BK=64 -> 32KB/CU-step unique.
// R12 skeleton: reg-staged, 2-deep ping-pong compiler-counted waits, XOR
// swizzle, 4 waves (2m x 2n), wave tile 64x64 (32 MFMA/step/wave).
#define BM 128
#define BN 128
#define BK 64
#define KSTEPS (NFEAT / BK)   // 32

typedef short  bf16x8 __attribute__((ext_vector_type(8)));
typedef float  f32x4  __attribute__((ext_vector_type(4)));

// ---------------- workspace layout (bytes) ----------------
#define OFF_W1F  ((size_t)0)
#define OFF_W2D  ((size_t)8388608)
#define OFF_W1B  ((size_t)8421376)       // bf16 W1 (4 MB)
#define OFF_XB   ((size_t)12615680)      // bf16 x (16 MB)

#define ZERO_FLOAT4 526336               // W1f+W2d contiguous
#define OUT_FLOAT4  (BATCH * NTGT / 4)   // 8192

__device__ __forceinline__ unsigned short f2bf(float f) {
    union { float f; unsigned int u; } a; a.f = f;
    unsigned int u = a.u;
    u += 0x7fffu + ((u >> 16) & 1u);   // round-to-nearest-even
    return (unsigned short)(u >> 16);
}

// zero W1f+W2d and pre-fill out with b2 (k_gemm atomicAdds into out)
__global__ void k_zero(float4* __restrict__ ws4, float4* __restrict__ out4,
                       const float* __restrict__ b2) {
    int i = blockIdx.x * blockDim.x + threadIdx.x;
    if (i < ZERO_FLOAT4) {
        ws4[i] = make_float4(0.f, 0.f, 0.f, 0.f);
    } else {
        int j = i - ZERO_FLOAT4;
        if (j < OUT_FLOAT4) {
            int p = (j & 1) * 4;
            out4[j] = make_float4(b2[p], b2[p + 1], b2[p + 2], b2[p + 3]);
        }
    }
}

// scatter-add edges into dense W1f and W2d (handles duplicate edges by summing)
__global__ void k_build(const float* __restrict__ w1, const int* __restrict__ c1o,
                        const int* __restrict__ c1i,
                        const float* __restrict__ w2, const int* __restrict__ c2o,
                        const int* __restrict__ c2i,
                        float* __restrict__ W1f, float* __restrict__ W2d) {
    int i = blockIdx.x * blockDim.x + threadIdx.x;
    if (i < NNZ1) {
        atomicAdd(&W1f[(size_t)c1o[i] * NFEAT + c1i[i]], w1[i]);
    } else {
        int j = i - NNZ1;
        if (j < NNZ2) atomicAdd(&W2d[c2i[j] * NTGT + c2o[j]], w2[j]);
    }
}

// convert W1f -> W1b and x -> xb (bf16 row-major), float4 -> 4x bf16 per thread
__global__ void k_convert(const float* __restrict__ W1f, const float* __restrict__ x,
                          unsigned short* __restrict__ W1b, unsigned short* __restrict__ xb) {
    int i = blockIdx.x * blockDim.x + threadIdx.x;
    const int nW = NNEUR * NFEAT / 4;
    const int nX = BATCH * NFEAT / 4;
    if (i < nW) {
        float4 v = ((const float4*)W1f)[i];
        ushort4 o;
        o.x = f2bf(v.x); o.y = f2bf(v.y); o.z = f2bf(v.z); o.w = f2bf(v.w);
        ((ushort4*)W1b)[i] = o;
    } else if (i < nW + nX) {
        int j = i - nW;
        float4 v = ((const float4*)x)[j];
        ushort4 o;
        o.x = f2bf(v.x); o.y = f2bf(v.y); o.z = f2bf(v.z); o.w = f2bf(v.w);
        ((ushort4*)xb)[j] = o;
    }
}

// bf16 MFMA GEMM, 128x128 tile, wave 64x64, reg-staged 2-deep
// compiler-scheduled pipeline, fused bias+sigmoid+layer2 epilogue (atomics).
__global__ __launch_bounds__(256) void k_gemm(const unsigned short* __restrict__ W1b,
                                              const unsigned short* __restrict__ xb,
                                              const float* __restrict__ b1,
                                              const float* __restrict__ W2d,
                                              float* __restrict__ out) {
    __shared__ unsigned short ldsA[2][BM * BK];   // 2 x 16 KB
    __shared__ unsigned short ldsB[2][BN * BK];   // 2 x 16 KB

    // bijective XCD swizzle: each XCD gets 4 contiguous n-tiles x 8 m-tiles
    int bid  = blockIdx.x;                 // 0..255
    int virt = (bid & 7) * 32 + (bid >> 3);
    int n0 = (virt >> 3) * BN;             // 32 n-tiles
    int mt = virt & 7;                     // 8 m-tiles
    int m0 = mt * BM;

    int tid  = threadIdx.x;
    int wv   = tid >> 6;
    int lane = tid & 63;
    int wm = wv >> 1, wn = wv & 1;         // wave grid 2m x 2n, wave tile 64x64
    int lr = lane & 15, lg = lane >> 4;

    f32x4 acc[4][4];
#pragma unroll
    for (int i = 0; i < 4; ++i)
#pragma unroll
        for (int j = 0; j < 4; ++j) acc[i][j] = (f32x4){0.f, 0.f, 0.f, 0.f};

    // ---- staging geometry ----
    // Tile 128x64 bf16 = 1024 16B-units; unit u: row=u>>3, slot s=u&7.
    // LDS unit = row*8 + (s ^ (row&7)) (XOR swizzle).
    // Thread t handles units t, t+256, t+512, t+768 (rows r0+32c, same XOR).
    int r0 = tid >> 3, s0 = tid & 7;
    const unsigned short* gA0 = &W1b[(size_t)(m0 + r0) * NFEAT + s0 * 8];
    const unsigned short* gA1 = gA0 + 32 * NFEAT;
    const unsigned short* gA2 = gA0 + 64 * NFEAT;
    const unsigned short* gA3 = gA0 + 96 * NFEAT;
    const unsigned short* gB0 = &xb[(size_t)(n0 + r0) * NFEAT + s0 * 8];
    const unsigned short* gB1 = gB0 + 32 * NFEAT;
    const unsigned short* gB2 = gB0 + 64 * NFEAT;
    const unsigned short* gB3 = gB0 + 96 * NFEAT;
    const int iw0 = r0 * 8 + (s0 ^ (r0 & 7));
    const int iw1 = iw0 + 256, iw2 = iw0 + 512, iw3 = iw0 + 768;

    // two named register sets (rule #20)
    bf16x8 A0a, A0b, A0c, A0d, B0a, B0b, B0c, B0d;
    bf16x8 A1a, A1b, A1c, A1d, B1a, B1b, B1c, B1d;
    bf16x8 af[4], bg[4];

#define LOADS0(T) do { int kk = (T) * BK;                           \
        A0a = *(const bf16x8*)(gA0 + kk); A0b = *(const bf16x8*)(gA1 + kk); \
        A0c = *(const bf16x8*)(gA2 + kk); A0d = *(const bf16x8*)(gA3 + kk); \
        B0a = *(const bf16x8*)(gB0 + kk); B0b = *(const bf16x8*)(gB1 + kk); \
        B0c = *(const bf16x8*)(gB2 + kk); B0d = *(const bf16x8*)(gB3 + kk); } while (0)
#define LOADS1(T) do { int kk = (T) * BK;                           \
        A1a = *(const bf16x8*)(gA0 + kk); A1b = *(const bf16x8*)(gA1 + kk); \
        A1c = *(const bf16x8*)(gA2 + kk); A1d = *(const bf16x8*)(gA3 + kk); \
        B1a = *(const bf16x8*)(gB0 + kk); B1b = *(const bf16x8*)(gB1 + kk); \
        B1c = *(const bf16x8*)(gB2 + kk); B1d = *(const bf16x8*)(gB3 + kk); } while (0)

#define STORE0(BUF) do {                                            \
        bf16x8* dA = (bf16x8*)&ldsA[BUF][0];                        \
        bf16x8* dB = (bf16x8*)&ldsB[BUF][0];                        \
        dA[iw0] = A0a; dA[iw1] = A0b; dA[iw2] = A0c; dA[iw3] = A0d; \
        dB[iw0] = B0a; dB[iw1] = B0b; dB[iw2] = B0c; dB[iw3] = B0d; } while (0)
#define STORE1(BUF) do {                                            \
        bf16x8* dA = (bf16x8*)&ldsA[BUF][0];                        \
        bf16x8* dB = (bf16x8*)&ldsB[BUF][0];                        \
        dA[iw0] = A1a; dA[iw1] = A1b; dA[iw2] = A1c; dA[iw3] = A1d; \
        dB[iw0] = B1a; dB[iw1] = B1b; dB[iw2] = B1c; dB[iw3] = B1d; } while (0)

    // read frags for k-slot KS (0/1) and run 16 MFMAs
#define HALF(BUF, KS) do {                                          \
        const unsigned short* bA = ldsA[BUF];                       \
        const unsigned short* bB = ldsB[BUF];                       \
        _Pragma("unroll")                                           \
        for (int f = 0; f < 4; ++f) {                               \
            int ra = wm * 64 + f * 16 + lr;                         \
            af[f] = *(const bf16x8*)&bA[(ra * 8 + (((KS) * 4 + lg) ^ (ra & 7))) * 8]; \
            int rb = wn * 64 + f * 16 + lr;                         \
            bg[f] = *(const bf16x8*)&bB[(rb * 8 + (((KS) * 4 + lg) ^ (rb & 7))) * 8]; \
        }                                                           \
        _Pragma("unroll")                                           \
        for (int i = 0; i < 4; ++i)                                 \
            _Pragma("unroll")                                       \
            for (int j = 0; j < 4; ++j)                             \
                acc[i][j] = __builtin_amdgcn_mfma_f32_16x16x32_bf16(af[i], bg[j], acc[i][j], 0, 0, 0); \
    } while (0)

#define COMPUTE(BUF) do { HALF(BUF, 0); HALF(BUF, 1); } while (0)

#define LDSFENCE() asm volatile("s_waitcnt lgkmcnt(0)" ::: "memory")

    // prologue: tiles 0,1 -> regs; store tile 0 (set1 loads stay in flight)
    LOADS0(0);
    LOADS1(1);
    STORE0(0);            // compiler waits set0's vmcnt precisely
    LDSFENCE();
    __builtin_amdgcn_s_barrier();

    // steady state: 15 pairs cover tiles 0..29.
#pragma unroll 1
    for (int p = 0; p < 15; ++p) {
        int e = 2 * p;
        LOADS0(e + 2);
        STORE1(1);        // waits set1 only (set0 stays in flight)
        COMPUTE(0);
        LDSFENCE();
        __builtin_amdgcn_s_barrier();
        LOADS1(e + 3);
        STORE0(0);
        COMPUTE(1);
        LDSFENCE();
        __builtin_amdgcn_s_barrier();
    }
    // tail: buf0 = tile 30 ready; set1 = tile 31 in flight
    STORE1(1);
    COMPUTE(0);
    LDSFENCE();
    __builtin_amdgcn_s_barrier();
    COMPUTE(1);

#undef LOADS0
#undef LOADS1
#undef STORE0
#undef STORE1
#undef HALF
#undef COMPUTE
#undef LDSFENCE

    // ---- fused epilogue (R16-verified): h = sigmoid(acc + b1);
    // pt[j][t] = sum_m h*W2d[m][t]; atomicAdd into b2-prefilled out.
    // C/D layout: col(n) = lane&15, row(m) = (lane>>4)*4 + reg  [m89-verified]
    float pt[4][NTGT];
#pragma unroll
    for (int j = 0; j < 4; ++j)
#pragma unroll
        for (int t = 0; t < NTGT; ++t) pt[j][t] = 0.f;

#pragma unroll
    for (int i = 0; i < 4; ++i) {
#pragma unroll
        for (int r = 0; r < 4; ++r) {
            int m = m0 + wm * 64 + i * 16 + lg * 4 + r;
            float bn = b1[m];
            float4 w2lo = *(const float4*)&W2d[m * NTGT];
            float4 w2hi = *(const float4*)&W2d[m * NTGT + 4];
#pragma unroll
            for (int j = 0; j < 4; ++j) {
                float h = 1.f / (1.f + __expf(-(acc[i][j][r] + bn)));
                pt[j][0] += h * w2lo.x; pt[j][1] += h * w2lo.y;
                pt[j][2] += h * w2lo.z; pt[j][3] += h * w2lo.w;
                pt[j][4] += h * w2hi.x; pt[j][5] += h * w2hi.y;
                pt[j][6] += h * w2hi.z; pt[j][7] += h * w2hi.w;
            }
        }
    }
    // reduce over lg (lanes lr+16*lg share the same n column)
#pragma unroll
    for (int j = 0; j < 4; ++j)
#pragma unroll
        for (int t = 0; t < NTGT; ++t) {
            float val = pt[j][t];
            val += __shfl_xor(val, 16, 64);
            val += __shfl_xor(val, 32, 64);
            pt[j][t] = val;
        }
    if (lg == 0) {
#pragma unroll
        for (int j = 0; j < 4; ++j) {
            int n = n0 + wn * 64 + j * 16 + lr;
#pragma unroll
            for (int t = 0; t < NTGT; ++t)
                atomicAdd(&out[(size_t)n * NTGT + t], pt[j][t]);
        }
    }
}

extern "C" void kernel_launch(void* const* d_in, const int* in_sizes, int n_in,
                              void* d_out, int out_size, void* d_ws, size_t ws_size,
                              hipStream_t stream) {
    (void)in_sizes; (void)n_in; (void)out_size; (void)ws_size;
    const float* x   = (const float*)d_in[0];
    const float* w1  = (const float*)d_in[1];
    const float* b1  = (const float*)d_in[2];
    const float* w2  = (const float*)d_in[3];
    const float* b2  = (const float*)d_in[4];
    const int*   c1o = (const int*)d_in[5];
    const int*   c1i = (const int*)d_in[6];
    const int*   c2o = (const int*)d_in[7];
    const int*   c2i = (const int*)d_in[8];
    float* out = (float*)d_out;

    char* ws = (char*)d_ws;
    float*          W1f  = (float*)(ws + OFF_W1F);
    float*          W2d  = (float*)(ws + OFF_W2D);
    unsigned short* W1b  = (unsigned short*)(ws + OFF_W1B);
    unsigned short* xb   = (unsigned short*)(ws + OFF_XB);

    // zero W1f+W2d, pre-fill out with b2
    k_zero<<<(ZERO_FLOAT4 + OUT_FLOAT4 + 255) / 256, 256, 0, stream>>>(
        (float4*)ws, (float4*)out, b2);

    // dense weight build
    k_build<<<(NNZ1 + NNZ2) / 256, 256, 0, stream>>>(w1, c1o, c1i, w2, c2o, c2i, W1f, W2d);

    // fp32 -> bf16 for BOTH operands (halves GEMM VMEM bytes)
    k_convert<<<(NNEUR * NFEAT / 4 + BATCH * NFEAT / 4) / 256, 256, 0, stream>>>(W1f, x, W1b, xb);

    // GEMM + bias + sigmoid + layer-2 (atomic) all fused
    k_gemm<<<(NNEUR / BM) * (BATCH / BN), 256, 0, stream>>>(W1b, xb, b1, W2d, out);
}

// Round 18
// 65.935 us; speedup vs baseline: 1.1059x; 1.1059x over previous
//
#include <hip/hip_runtime.h>
#include <math.h>

// Problem constants
#define BATCH 4096
#define NFEAT 2048
#define NNEUR 1024
#define NTGT  8
#define NNZ1  65536
#define NNZ2  8192

// out[n][t] = b2[t] + sum_m sigmoid(sum_k W1[m][k]x[n][k] + b1[m]) * W2[m][t]
// BARRIER-FREE GEMM + IN-BLOCK SPLIT-K (R17 post-mortem: barrier-free chain
// was the best per-step structure; it lacked a 2nd wave/SIMD to interleave).
// Both operands pre-packed in MFMA-fragment order; fragments load
// global->registers (no LDS, no barriers in the K-loop). Block = 8 waves =
// 4 n-subtiles x 2 K-halves; each wave: 64x64 tile over K/2 (32 steps of
// K=32, 16 MFMA/step). 2048 waves = 2/SIMD. One LDS combine + epilogue.
#define KH_STEPS 32   // K-steps per wave (half of 64)

typedef short  bf16x8 __attribute__((ext_vector_type(8)));
typedef float  f32x4  __attribute__((ext_vector_type(4)));

// ---------------- workspace layout (bytes) ----------------
#define OFF_W1F  ((size_t)0)
#define OFF_W2D  ((size_t)8388608)
#define OFF_W1P  ((size_t)8421376)       // fragment-packed W1 (4 MB)
#define OFF_XP   ((size_t)12615680)      // fragment-packed x  (16 MB)

#define ZERO_FLOAT4 526336               // W1f+W2d contiguous
#define OUT_FLOAT4  (BATCH * NTGT / 4)   // 8192
#define NPACKW (NNEUR * NFEAT / 8)       // 262144 units
#define NPACKX (BATCH * NFEAT / 8)       // 1048576 units

// 8x f32 -> 8x bf16 (RNE) packed in uint4, via v_cvt_pk_bf16_f32
__device__ __forceinline__ uint4 pk8(float4 lo, float4 hi) {
    uint4 r;
    asm("v_cvt_pk_bf16_f32 %0, %1, %2" : "=v"(r.x) : "v"(lo.x), "v"(lo.y));
    asm("v_cvt_pk_bf16_f32 %0, %1, %2" : "=v"(r.y) : "v"(lo.z), "v"(lo.w));
    asm("v_cvt_pk_bf16_f32 %0, %1, %2" : "=v"(r.z) : "v"(hi.x), "v"(hi.y));
    asm("v_cvt_pk_bf16_f32 %0, %1, %2" : "=v"(r.w) : "v"(hi.z), "v"(hi.w));
    return r;
}

// zero W1f+W2d and pre-fill out with b2 (k_gemm atomicAdds into out)
__global__ void k_zero(float4* __restrict__ ws4, float4* __restrict__ out4,
                       const float* __restrict__ b2) {
    int i = blockIdx.x * blockDim.x + threadIdx.x;
    if (i < ZERO_FLOAT4) {
        ws4[i] = make_float4(0.f, 0.f, 0.f, 0.f);
    } else {
        int j = i - ZERO_FLOAT4;
        if (j < OUT_FLOAT4) {
            int p = (j & 1) * 4;
            out4[j] = make_float4(b2[p], b2[p + 1], b2[p + 2], b2[p + 3]);
        }
    }
}

// scatter-add edges into dense W1f and W2d (handles duplicate edges by summing)
__global__ void k_build(const float* __restrict__ w1, const int* __restrict__ c1o,
                        const int* __restrict__ c1i,
                        const float* __restrict__ w2, const int* __restrict__ c2o,
                        const int* __restrict__ c2i,
                        float* __restrict__ W1f, float* __restrict__ W2d) {
    int i = blockIdx.x * blockDim.x + threadIdx.x;
    if (i < NNZ1) {
        atomicAdd(&W1f[(size_t)c1o[i] * NFEAT + c1i[i]], w1[i]);
    } else {
        int j = i - NNZ1;
        if (j < NNZ2) atomicAdd(&W2d[c2i[j] * NTGT + c2o[j]], w2[j]);
    }
}

// pack BOTH W1f and x into per-step MFMA fragment order (bf16), one kernel.
// unit u: lane=u&63, frag=(u>>6)&3, T=(u>>8)&63, panel=u>>14
//   row = panel*64 + frag*16 + (lane&15), k = T*32 + (lane>>4)*8
// => wave (panel) step T frag f = units [panel*16384 + T*256 + f*64 .. +64):
//    one fully-coalesced 1KB read. [layout verified: R16 passed absmax]
__global__ void k_packall(const float* __restrict__ W1f, const float* __restrict__ x,
                          unsigned short* __restrict__ W1p, unsigned short* __restrict__ xp) {
    int g = blockIdx.x * blockDim.x + threadIdx.x;
    const float* src_base;
    uint4* dst;
    int u;
    if (g < NPACKW) { u = g;          src_base = W1f; dst = (uint4*)W1p; }
    else            { u = g - NPACKW; src_base = x;   dst = (uint4*)xp;  }
    int lane = u & 63;
    int f    = (u >> 6) & 3;
    int T    = (u >> 8) & 63;
    int pn   = u >> 14;
    int row = pn * 64 + f * 16 + (lane & 15);
    int k   = T * 32 + (lane >> 4) * 8;
    const float* src = &src_base[(size_t)row * NFEAT + k];
    float4 lo = *(const float4*)src;
    float4 hi = *(const float4*)(src + 4);
    dst[u] = pk8(lo, hi);
}

// Barrier-free bf16 MFMA GEMM, in-block split-K, fused epilogue.
__global__ __launch_bounds__(512) void k_gemm(const unsigned short* __restrict__ W1p,
                                              const unsigned short* __restrict__ xp,
                                              const float* __restrict__ b1,
                                              const float* __restrict__ W2d,
                                              float* __restrict__ out) {
    __shared__ float cmb[4][4096];         // 64 KB combine scratch

    // XCD map (R16): xcd = bid&7 owns 2 n-quarters; bijective over 256 blocks.
    int bid = blockIdx.x;
    int xcd = bid & 7;
    int i5  = bid >> 3;                    // 0..31
    int nq  = xcd * 2 + (i5 & 1);          // 0..15 (256-col group)
    int mp  = i5 >> 1;                     // 0..15 (64-row A panel)

    int tid  = threadIdx.x;
    int wv   = tid >> 6;                   // 0..7
    int lane = tid & 63;
    int jw = wv & 3;                       // n-subtile
    int kh = wv >> 2;                      // K-half
    int nb = nq * 4 + jw;                  // wave's 64-col n-group
    int lr = lane & 15, lg = lane >> 4;

    // fragment streams for this wave's K-half (T local 0..31)
    const bf16x8* gA = (const bf16x8*)W1p + (size_t)mp * 16384 + (size_t)kh * 32 * 256 + lane;
    const bf16x8* gB = (const bf16x8*)xp  + (size_t)nb * 16384 + (size_t)kh * 32 * 256 + lane;

    f32x4 acc[4][4];
#pragma unroll
    for (int i = 0; i < 4; ++i)
#pragma unroll
        for (int j = 0; j < 4; ++j) acc[i][j] = (f32x4){0.f, 0.f, 0.f, 0.f};

    // two named register sets; no LDS, no barriers — compiler pipelines with
    // precisely-counted vmcnt (loads for T+2 issue right after MFMAs of T).
    bf16x8 A0[4], B0[4], A1[4], B1[4];

#define LOADS0(T) do {                                              \
        _Pragma("unroll")                                           \
        for (int c = 0; c < 4; ++c) {                               \
            A0[c] = gA[(T) * 256 + c * 64];                         \
            B0[c] = gB[(T) * 256 + c * 64];                         \
        } } while (0)
#define LOADS1(T) do {                                              \
        _Pragma("unroll")                                           \
        for (int c = 0; c < 4; ++c) {                               \
            A1[c] = gA[(T) * 256 + c * 64];                         \
            B1[c] = gB[(T) * 256 + c * 64];                         \
        } } while (0)
#define MFMAS0() do {                                               \
        _Pragma("unroll")                                           \
        for (int i = 0; i < 4; ++i)                                 \
            _Pragma("unroll")                                       \
            for (int j = 0; j < 4; ++j)                             \
                acc[i][j] = __builtin_amdgcn_mfma_f32_16x16x32_bf16(A0[i], B0[j], acc[i][j], 0, 0, 0); \
    } while (0)
#define MFMAS1() do {                                               \
        _Pragma("unroll")                                           \
        for (int i = 0; i < 4; ++i)                                 \
            _Pragma("unroll")                                       \
            for (int j = 0; j < 4; ++j)                             \
                acc[i][j] = __builtin_amdgcn_mfma_f32_16x16x32_bf16(A1[i], B1[j], acc[i][j], 0, 0, 0); \
    } while (0)

    LOADS0(0);
    LOADS1(1);
    // 15 pairs cover steps 0..29; loads run 2 steps ahead.
#pragma unroll 1
    for (int p = 0; p < 15; ++p) {
        MFMAS0();
        LOADS0(2 * p + 2);
        MFMAS1();
        LOADS1(2 * p + 3);
    }
    MFMAS0();   // step 30
    MFMAS1();   // step 31

#undef LOADS0
#undef LOADS1
#undef MFMAS0
#undef MFMAS1

    // ---- K-half combine: kh=1 waves dump acc to LDS; kh=0 add ----
    if (kh == 1) {
#pragma unroll
        for (int i = 0; i < 4; ++i)
#pragma unroll
            for (int j = 0; j < 4; ++j)
                *(f32x4*)&cmb[jw][(i * 4 + j) * 256 + lane * 4] = acc[i][j];
    }
    __syncthreads();
    if (kh == 1) return;

#pragma unroll
    for (int i = 0; i < 4; ++i)
#pragma unroll
        for (int j = 0; j < 4; ++j)
            acc[i][j] += *(const f32x4*)&cmb[jw][(i * 4 + j) * 256 + lane * 4];

    // ---- fused epilogue (R16-verified): h = sigmoid(acc + b1);
    // pt[j][t] = sum_m h*W2d[m][t]; atomicAdd into b2-prefilled out.
    // C/D layout: col(n) = lane&15, row(m) = (lane>>4)*4 + reg  [m89-verified]
    float pt[4][NTGT];
#pragma unroll
    for (int j = 0; j < 4; ++j)
#pragma unroll
        for (int t = 0; t < NTGT; ++t) pt[j][t] = 0.f;

#pragma unroll
    for (int i = 0; i < 4; ++i) {
#pragma unroll
        for (int r = 0; r < 4; ++r) {
            int m = mp * 64 + i * 16 + lg * 4 + r;
            float bn = b1[m];
            float4 w2lo = *(const float4*)&W2d[m * NTGT];
            float4 w2hi = *(const float4*)&W2d[m * NTGT + 4];
#pragma unroll
            for (int j = 0; j < 4; ++j) {
                float h = 1.f / (1.f + __expf(-(acc[i][j][r] + bn)));
                pt[j][0] += h * w2lo.x; pt[j][1] += h * w2lo.y;
                pt[j][2] += h * w2lo.z; pt[j][3] += h * w2lo.w;
                pt[j][4] += h * w2hi.x; pt[j][5] += h * w2hi.y;
                pt[j][6] += h * w2hi.z; pt[j][7] += h * w2hi.w;
            }
        }
    }
    // reduce over lg (lanes lr+16*lg share the same n column)
#pragma unroll
    for (int j = 0; j < 4; ++j)
#pragma unroll
        for (int t = 0; t < NTGT; ++t) {
            float val = pt[j][t];
            val += __shfl_xor(val, 16, 64);
            val += __shfl_xor(val, 32, 64);
            pt[j][t] = val;
        }
    if (lg == 0) {
#pragma unroll
        for (int j = 0; j < 4; ++j) {
            int n = nb * 64 + j * 16 + lr;
#pragma unroll
            for (int t = 0; t < NTGT; ++t)
                atomicAdd(&out[(size_t)n * NTGT + t], pt[j][t]);
        }
    }
}

extern "C" void kernel_launch(void* const* d_in, const int* in_sizes, int n_in,
                              void* d_out, int out_size, void* d_ws, size_t ws_size,
                              hipStream_t stream) {
    (void)in_sizes; (void)n_in; (void)out_size; (void)ws_size;
    const float* x   = (const float*)d_in[0];
    const float* w1  = (const float*)d_in[1];
    const float* b1  = (const float*)d_in[2];
    const float* w2  = (const float*)d_in[3];
    const float* b2  = (const float*)d_in[4];
    const int*   c1o = (const int*)d_in[5];
    const int*   c1i = (const int*)d_in[6];
    const int*   c2o = (const int*)d_in[7];
    const int*   c2i = (const int*)d_in[8];
    float* out = (float*)d_out;

    char* ws = (char*)d_ws;
    float*          W1f  = (float*)(ws + OFF_W1F);
    float*          W2d  = (float*)(ws + OFF_W2D);
    unsigned short* W1p  = (unsigned short*)(ws + OFF_W1P);
    unsigned short* xp   = (unsigned short*)(ws + OFF_XP);

    // zero W1f+W2d, pre-fill out with b2
    k_zero<<<(ZERO_FLOAT4 + OUT_FLOAT4 + 255) / 256, 256, 0, stream>>>(
        (float4*)ws, (float4*)out, b2);

    // dense weight build
    k_build<<<(NNZ1 + NNZ2) / 256, 256, 0, stream>>>(w1, c1o, c1i, w2, c2o, c2i, W1f, W2d);

    // pack W1 and x into MFMA-fragment order (bf16), one kernel
    k_packall<<<(NPACKW + NPACKX) / 256, 256, 0, stream>>>(W1f, x, W1p, xp);

    // barrier-free split-K GEMM + bias + sigmoid + layer-2 (atomic) fused
    k_gemm<<<256, 512, 0, stream>>>(W1p, xp, b1, W2d, out);
}

// Round 19
// 64.243 us; speedup vs baseline: 1.1350x; 1.0263x over previous
//
#include <hip/hip_runtime.h>
#include <math.h>

// Problem constants
#define BATCH 4096
#define NFEAT 2048
#define NNEUR 1024
#define NTGT  8
#define NNZ1  65536
#define NNZ2  8192

// out[n][t] = b2[t] + sum_m sigmoid(sum_k W1[m][k]x[n][k] + b1[m]) * W2[m][t]
// Min-VMEM-instruction GEMM (R18 post-mortem: all designs pinned at ~48cyc
// per 1KB wave-load; floor = insts*48/256CU given >=2 waves/SIMD):
// 128x128 tile, bf16 BOTH operands, BK=64 -> 262144 total wave-loads
// (half of R12/R16/R18). 512 threads = 8 waves (2m x 4n, wave 64x32,
// 2 waves/SIMD -- R17's failure was running this tile at 1 wave/SIMD).
// R12 skeleton: reg-staged, 2-deep ping-pong, compiler-counted waits,
// XOR-swizzled LDS. R16's verified atomic epilogue. Grid 256 = 1 block/CU.
#define BM 128
#define BN 128
#define BK 64
#define KSTEPS (NFEAT / BK)   // 32

typedef short  bf16x8 __attribute__((ext_vector_type(8)));
typedef float  f32x4  __attribute__((ext_vector_type(4)));

// ---------------- workspace layout (bytes) ----------------
#define OFF_W1F  ((size_t)0)
#define OFF_W2D  ((size_t)8388608)
#define OFF_W1B  ((size_t)8421376)       // bf16 W1 (4 MB)
#define OFF_XB   ((size_t)12615680)      // bf16 x (16 MB)

#define ZERO_FLOAT4 526336               // W1f+W2d contiguous
#define OUT_FLOAT4  (BATCH * NTGT / 4)   // 8192

__device__ __forceinline__ unsigned short f2bf(float f) {
    union { float f; unsigned int u; } a; a.f = f;
    unsigned int u = a.u;
    u += 0x7fffu + ((u >> 16) & 1u);   // round-to-nearest-even
    return (unsigned short)(u >> 16);
}

// zero W1f+W2d and pre-fill out with b2 (k_gemm atomicAdds into out)
__global__ void k_zero(float4* __restrict__ ws4, float4* __restrict__ out4,
                       const float* __restrict__ b2) {
    int i = blockIdx.x * blockDim.x + threadIdx.x;
    if (i < ZERO_FLOAT4) {
        ws4[i] = make_float4(0.f, 0.f, 0.f, 0.f);
    } else {
        int j = i - ZERO_FLOAT4;
        if (j < OUT_FLOAT4) {
            int p = (j & 1) * 4;
            out4[j] = make_float4(b2[p], b2[p + 1], b2[p + 2], b2[p + 3]);
        }
    }
}

// scatter-add edges into dense W1f and W2d (handles duplicate edges by summing)
__global__ void k_build(const float* __restrict__ w1, const int* __restrict__ c1o,
                        const int* __restrict__ c1i,
                        const float* __restrict__ w2, const int* __restrict__ c2o,
                        const int* __restrict__ c2i,
                        float* __restrict__ W1f, float* __restrict__ W2d) {
    int i = blockIdx.x * blockDim.x + threadIdx.x;
    if (i < NNZ1) {
        atomicAdd(&W1f[(size_t)c1o[i] * NFEAT + c1i[i]], w1[i]);
    } else {
        int j = i - NNZ1;
        if (j < NNZ2) atomicAdd(&W2d[c2i[j] * NTGT + c2o[j]], w2[j]);
    }
}

// convert W1f -> W1b and x -> xb (bf16 row-major), float4 -> 4x bf16, coalesced
__global__ void k_convert(const float* __restrict__ W1f, const float* __restrict__ x,
                          unsigned short* __restrict__ W1b, unsigned short* __restrict__ xb) {
    int i = blockIdx.x * blockDim.x + threadIdx.x;
    const int nW = NNEUR * NFEAT / 4;
    const int nX = BATCH * NFEAT / 4;
    if (i < nW) {
        float4 v = ((const float4*)W1f)[i];
        ushort4 o;
        o.x = f2bf(v.x); o.y = f2bf(v.y); o.z = f2bf(v.z); o.w = f2bf(v.w);
        ((ushort4*)W1b)[i] = o;
    } else if (i < nW + nX) {
        int j = i - nW;
        float4 v = ((const float4*)x)[j];
        ushort4 o;
        o.x = f2bf(v.x); o.y = f2bf(v.y); o.z = f2bf(v.z); o.w = f2bf(v.w);
        ((ushort4*)xb)[j] = o;
    }
}

// bf16 MFMA GEMM, 128x128 tile, 8 waves, reg-staged 2-deep compiler-scheduled
// pipeline, fused bias+sigmoid+layer2 epilogue (atomic into out).
__global__ __launch_bounds__(512) void k_gemm(const unsigned short* __restrict__ W1b,
                                              const unsigned short* __restrict__ xb,
                                              const float* __restrict__ b1,
                                              const float* __restrict__ W2d,
                                              float* __restrict__ out) {
    __shared__ unsigned short ldsA[2][BM * BK];   // 2 x 16 KB
    __shared__ unsigned short ldsB[2][BN * BK];   // 2 x 16 KB

    // bijective XCD swizzle: each XCD gets 4 contiguous n-tiles x 8 m-tiles
    int bid  = blockIdx.x;                 // 0..255
    int virt = (bid & 7) * 32 + (bid >> 3);
    int n0 = (virt >> 3) * BN;             // 32 n-tiles
    int mt = virt & 7;                     // 8 m-tiles
    int m0 = mt * BM;

    int tid  = threadIdx.x;
    int wv   = tid >> 6;                   // 8 waves
    int lane = tid & 63;
    int wm = wv >> 2, wn = wv & 3;         // wave grid 2m x 4n, wave tile 64x32
    int lr = lane & 15, lg = lane >> 4;

    f32x4 acc[4][2];
#pragma unroll
    for (int i = 0; i < 4; ++i)
#pragma unroll
        for (int j = 0; j < 2; ++j) acc[i][j] = (f32x4){0.f, 0.f, 0.f, 0.f};

    // ---- staging geometry ----
    // Tile 128x64 bf16 = 1024 16B-units; unit u: row=u>>3, slot s=u&7.
    // LDS unit = row*8 + (s ^ (row&7)) (XOR swizzle).
    // 512 threads: thread t handles units t, t+512 (rows r0, r0+64: same XOR).
    // Per thread per tile: 2 A-loads + 2 B-loads = 4 VMEM insts (minimum).
    int r0 = tid >> 3, s0 = tid & 7;
    const unsigned short* gA0 = &W1b[(size_t)(m0 + r0) * NFEAT + s0 * 8];
    const unsigned short* gA1 = gA0 + 64 * NFEAT;
    const unsigned short* gB0 = &xb[(size_t)(n0 + r0) * NFEAT + s0 * 8];
    const unsigned short* gB1 = gB0 + 64 * NFEAT;
    const int iw0 = r0 * 8 + (s0 ^ (r0 & 7));
    const int iw1 = iw0 + 512;

    // two named register sets (rule #20)
    bf16x8 A0a, A0b, B0a, B0b;
    bf16x8 A1a, A1b, B1a, B1b;
    bf16x8 af[4], bg[2];

#define LOADS0(T) do { int kk = (T) * BK;                           \
        A0a = *(const bf16x8*)(gA0 + kk); A0b = *(const bf16x8*)(gA1 + kk); \
        B0a = *(const bf16x8*)(gB0 + kk); B0b = *(const bf16x8*)(gB1 + kk); } while (0)
#define LOADS1(T) do { int kk = (T) * BK;                           \
        A1a = *(const bf16x8*)(gA0 + kk); A1b = *(const bf16x8*)(gA1 + kk); \
        B1a = *(const bf16x8*)(gB0 + kk); B1b = *(const bf16x8*)(gB1 + kk); } while (0)

#define STORE0(BUF) do {                                            \
        bf16x8* dA = (bf16x8*)&ldsA[BUF][0];                        \
        bf16x8* dB = (bf16x8*)&ldsB[BUF][0];                        \
        dA[iw0] = A0a; dA[iw1] = A0b;                               \
        dB[iw0] = B0a; dB[iw1] = B0b; } while (0)
#define STORE1(BUF) do {                                            \
        bf16x8* dA = (bf16x8*)&ldsA[BUF][0];                        \
        bf16x8* dB = (bf16x8*)&ldsB[BUF][0];                        \
        dA[iw0] = A1a; dA[iw1] = A1b;                               \
        dB[iw0] = B1a; dB[iw1] = B1b; } while (0)

    // frags for k-slot KS (0/1): af rows wm*64+f*16+lr, bg rows wn*32+j*16+lr
#define HALF(BUF, KS) do {                                          \
        const unsigned short* bA = ldsA[BUF];                       \
        const unsigned short* bB = ldsB[BUF];                       \
        _Pragma("unroll")                                           \
        for (int f = 0; f < 4; ++f) {                               \
            int ra = wm * 64 + f * 16 + lr;                         \
            af[f] = *(const bf16x8*)&bA[(ra * 8 + (((KS) * 4 + lg) ^ (ra & 7))) * 8]; \
        }                                                           \
        _Pragma("unroll")                                           \
        for (int j = 0; j < 2; ++j) {                               \
            int rb = wn * 32 + j * 16 + lr;                         \
            bg[j] = *(const bf16x8*)&bB[(rb * 8 + (((KS) * 4 + lg) ^ (rb & 7))) * 8]; \
        }                                                           \
        _Pragma("unroll")                                           \
        for (int i = 0; i < 4; ++i)                                 \
            _Pragma("unroll")                                       \
            for (int j = 0; j < 2; ++j)                             \
                acc[i][j] = __builtin_amdgcn_mfma_f32_16x16x32_bf16(af[i], bg[j], acc[i][j], 0, 0, 0); \
    } while (0)

#define COMPUTE(BUF) do { HALF(BUF, 0); HALF(BUF, 1); } while (0)

#define LDSFENCE() asm volatile("s_waitcnt lgkmcnt(0)" ::: "memory")

    // prologue: tiles 0,1 -> regs; store tile 0 (set1 loads stay in flight)
    LOADS0(0);
    LOADS1(1);
    STORE0(0);            // compiler waits set0's vmcnt precisely
    LDSFENCE();
    __builtin_amdgcn_s_barrier();

    // steady state: 15 pairs cover tiles 0..29.
#pragma unroll 1
    for (int p = 0; p < 15; ++p) {
        int e = 2 * p;
        LOADS0(e + 2);
        STORE1(1);        // waits set1 only (set0 stays in flight)
        COMPUTE(0);
        LDSFENCE();
        __builtin_amdgcn_s_barrier();
        LOADS1(e + 3);
        STORE0(0);
        COMPUTE(1);
        LDSFENCE();
        __builtin_amdgcn_s_barrier();
    }
    // tail: buf0 = tile 30 ready; set1 = tile 31 in flight
    STORE1(1);
    COMPUTE(0);
    LDSFENCE();
    __builtin_amdgcn_s_barrier();
    COMPUTE(1);

#undef LOADS0
#undef LOADS1
#undef STORE0
#undef STORE1
#undef HALF
#undef COMPUTE
#undef LDSFENCE

    // ---- fused epilogue (R16-verified): h = sigmoid(acc + b1);
    // pt[j][t] = sum_m h*W2d[m][t]; atomicAdd into b2-prefilled out.
    // C/D layout: col(n) = lane&15, row(m) = (lane>>4)*4 + reg  [m89-verified]
    float pt[2][NTGT];
#pragma unroll
    for (int j = 0; j < 2; ++j)
#pragma unroll
        for (int t = 0; t < NTGT; ++t) pt[j][t] = 0.f;

#pragma unroll
    for (int i = 0; i < 4; ++i) {
#pragma unroll
        for (int r = 0; r < 4; ++r) {
            int m = m0 + wm * 64 + i * 16 + lg * 4 + r;
            float bn = b1[m];
            float4 w2lo = *(const float4*)&W2d[m * NTGT];
            float4 w2hi = *(const float4*)&W2d[m * NTGT + 4];
#pragma unroll
            for (int j = 0; j < 2; ++j) {
                float h = 1.f / (1.f + __expf(-(acc[i][j][r] + bn)));
                pt[j][0] += h * w2lo.x; pt[j][1] += h * w2lo.y;
                pt[j][2] += h * w2lo.z; pt[j][3] += h * w2lo.w;
                pt[j][4] += h * w2hi.x; pt[j][5] += h * w2hi.y;
                pt[j][6] += h * w2hi.z; pt[j][7] += h * w2hi.w;
            }
        }
    }
    // reduce over lg (lanes lr+16*lg share the same n column)
#pragma unroll
    for (int j = 0; j < 2; ++j)
#pragma unroll
        for (int t = 0; t < NTGT; ++t) {
            float val = pt[j][t];
            val += __shfl_xor(val, 16, 64);
            val += __shfl_xor(val, 32, 64);
            pt[j][t] = val;
        }
    if (lg == 0) {
#pragma unroll
        for (int j = 0; j < 2; ++j) {
            int n = n0 + wn * 32 + j * 16 + lr;
#pragma unroll
            for (int t = 0; t < NTGT; ++t)
                atomicAdd(&out[(size_t)n * NTGT + t], pt[j][t]);
        }
    }
}

extern "C" void kernel_launch(void* const* d_in, const int* in_sizes, int n_in,
                              void* d_out, int out_size, void* d_ws, size_t ws_size,
                              hipStream_t stream) {
    (void)in_sizes; (void)n_in; (void)out_size; (void)ws_size;
    const float* x   = (const float*)d_in[0];
    const float* w1  = (const float*)d_in[1];
    const float* b1  = (const float*)d_in[2];
    const float* w2  = (const float*)d_in[3];
    const float* b2  = (const float*)d_in[4];
    const int*   c1o = (const int*)d_in[5];
    const int*   c1i = (const int*)d_in[6];
    const int*   c2o = (const int*)d_in[7];
    const int*   c2i = (const int*)d_in[8];
    float* out = (float*)d_out;

    char* ws = (char*)d_ws;
    float*          W1f  = (float*)(ws + OFF_W1F);
    float*          W2d  = (float*)(ws + OFF_W2D);
    unsigned short* W1b  = (unsigned short*)(ws + OFF_W1B);
    unsigned short* xb   = (unsigned short*)(ws + OFF_XB);

    // zero W1f+W2d, pre-fill out with b2
    k_zero<<<(ZERO_FLOAT4 + OUT_FLOAT4 + 255) / 256, 256, 0, stream>>>(
        (float4*)ws, (float4*)out, b2);

    // dense weight build
    k_build<<<(NNZ1 + NNZ2) / 256, 256, 0, stream>>>(w1, c1o, c1i, w2, c2o, c2i, W1f, W2d);

    // fp32 -> bf16 for BOTH operands (min VMEM instructions in GEMM)
    k_convert<<<(NNEUR * NFEAT / 4 + BATCH * NFEAT / 4) / 256, 256, 0, stream>>>(W1f, x, W1b, xb);

    // GEMM + bias + sigmoid + layer-2 (atomic) all fused
    k_gemm<<<(NNEUR / BM) * (BATCH / BN), 512, 0, stream>>>(W1b, xb, b1, W2d, out);
}

// Round 20
// 50.611 us; speedup vs baseline: 1.4407x; 1.2694x over previous
//
#include <hip/hip_runtime.h>
#include <math.h>

// Problem constants
#define BATCH 4096
#define NFEAT 2048
#define NNEUR 1024
#define NTGT  8
#define NNZ1  65536
#define NNZ2  8192

// GEMM: h[m][n] = sigmoid( sum_k W1b[m][k]*xbf(n,k) + b1[m] ), fused layer-2
// epilogue (atomicAdd into b2-prefilled out). M=1024, N=4096, K=2048.
// FINAL (session-best, R12): register-staged, 2-tiles-in-flight pipeline with
// COMPILER-COUNTED waits (no sched_barrier/setprio/manual vmcnt — m141/m190);
// only manual asm is lgkmcnt(0) before each raw s_barrier. B read as f32 from
// x, cvt to bf16 in-register at LDS store (v_cvt_pk_bf16_f32) — no x pre-pass.
// 128x64 tile, BK=64 (32 steps), 256 thr (4 waves 2m x 2n, wave 64x32),
// grid 512 = 2 blocks/CU.
// Post-mortem of 17 structural variants: gemm pinned at 40±4us across 3x
// byte-traffic, 2x instruction, 1-4 waves/SIMD, 0-2 barriers/step => shape-
// family plateau (~430 TF eff; m102 reference for N=2048-equiv: 320 TF).
#define BM 128
#define BN 64
#define BK 64
#define KSTEPS (NFEAT / BK)   // 32

typedef short  bf16x8 __attribute__((ext_vector_type(8)));
typedef float  f32x4  __attribute__((ext_vector_type(4)));

// ---------------- workspace layout (bytes) ----------------
#define OFF_W1F  ((size_t)0)
#define OFF_W2D  ((size_t)8388608)
#define OFF_W1B  ((size_t)8421376)

#define ZERO_FLOAT4 526336               // W1f+W2d contiguous
#define OUT_FLOAT4  (BATCH * NTGT / 4)   // 8192

__device__ __forceinline__ unsigned short f2bf(float f) {
    union { float f; unsigned int u; } a; a.f = f;
    unsigned int u = a.u;
    u += 0x7fffu + ((u >> 16) & 1u);   // round-to-nearest-even
    return (unsigned short)(u >> 16);
}

// 8x f32 -> 8x bf16 (RNE) packed in uint4, via v_cvt_pk_bf16_f32
__device__ __forceinline__ uint4 pk8(float4 lo, float4 hi) {
    uint4 r;
    asm("v_cvt_pk_bf16_f32 %0, %1, %2" : "=v"(r.x) : "v"(lo.x), "v"(lo.y));
    asm("v_cvt_pk_bf16_f32 %0, %1, %2" : "=v"(r.y) : "v"(lo.z), "v"(lo.w));
    asm("v_cvt_pk_bf16_f32 %0, %1, %2" : "=v"(r.z) : "v"(hi.x), "v"(hi.y));
    asm("v_cvt_pk_bf16_f32 %0, %1, %2" : "=v"(r.w) : "v"(hi.z), "v"(hi.w));
    return r;
}

// zero W1f+W2d and pre-fill out with b2 (k_gemm atomicAdds into out)
__global__ void k_zero(float4* __restrict__ ws4, float4* __restrict__ out4,
                       const float* __restrict__ b2) {
    int i = blockIdx.x * blockDim.x + threadIdx.x;
    if (i < ZERO_FLOAT4) {
        ws4[i] = make_float4(0.f, 0.f, 0.f, 0.f);
    } else {
        int j = i - ZERO_FLOAT4;
        if (j < OUT_FLOAT4) {
            int p = (j & 1) * 4;
            out4[j] = make_float4(b2[p], b2[p + 1], b2[p + 2], b2[p + 3]);
        }
    }
}

// scatter-add edges into dense W1f and W2d (handles duplicate edges by summing)
__global__ void k_build(const float* __restrict__ w1, const int* __restrict__ c1o,
                        const int* __restrict__ c1i,
                        const float* __restrict__ w2, const int* __restrict__ c2o,
                        const int* __restrict__ c2i,
                        float* __restrict__ W1f, float* __restrict__ W2d) {
    int i = blockIdx.x * blockDim.x + threadIdx.x;
    if (i < NNZ1) {
        atomicAdd(&W1f[(size_t)c1o[i] * NFEAT + c1i[i]], w1[i]);
    } else {
        int j = i - NNZ1;
        if (j < NNZ2) atomicAdd(&W2d[c2i[j] * NTGT + c2o[j]], w2[j]);
    }
}

// convert W1f -> W1b only (x is consumed as f32 by k_gemm)
__global__ void k_convert(const float* __restrict__ W1f, unsigned short* __restrict__ W1b) {
    int i = blockIdx.x * blockDim.x + threadIdx.x;   // < NNEUR*NFEAT/4
    float4 v = ((const float4*)W1f)[i];
    ushort4 o;
    o.x = f2bf(v.x); o.y = f2bf(v.y); o.z = f2bf(v.z); o.w = f2bf(v.w);
    ((ushort4*)W1b)[i] = o;
}

// bf16 MFMA GEMM, reg-staged 2-deep compiler-scheduled pipeline,
// fused bias+sigmoid+layer2 epilogue (atomic into out).
__global__ __launch_bounds__(256) void k_gemm(const unsigned short* __restrict__ W1b,
                                              const float* __restrict__ x,
                                              const float* __restrict__ b1,
                                              const float* __restrict__ W2d,
                                              float* __restrict__ out) {
    __shared__ unsigned short ldsA[2][BM * BK];   // 2 x 16 KB
    __shared__ unsigned short ldsB[2][BN * BK];   // 2 x 8 KB
    __shared__ float s_w2[BM][NTGT];              // 4 KB
    __shared__ float s_b1[BM];                    // 512 B
    __shared__ float s_pt[2][BN][NTGT];           // 4 KB

    // bijective XCD swizzle: each XCD gets 8 contiguous n-tiles x 8 m-tiles
    int bid = blockIdx.x;                  // 0..511
    int v   = bid >> 3;                    // 0..63
    int n0  = ((bid & 7) * 8 + (v >> 3)) * BN;   // 64 n-tiles
    int mt  = v & 7;                       // 8 m-tiles
    int m0  = mt * BM;

    int tid  = threadIdx.x;
    int wv   = tid >> 6;
    int lane = tid & 63;
    int wm = wv >> 1, wn = wv & 1;         // wave grid 2m x 2n, wave tile 64x32
    int lr = lane & 15, lg = lane >> 4;

    // preload W2d + b1 slices for the epilogue (compiler orders via dataflow)
    for (int i = tid; i < BM * NTGT; i += 256)
        s_w2[i >> 3][i & 7] = W2d[(m0 + (i >> 3)) * NTGT + (i & 7)];
    if (tid < BM) s_b1[tid] = b1[m0 + tid];

    f32x4 zero4 = {0.f, 0.f, 0.f, 0.f};
    f32x4 acc[4][2];
#pragma unroll
    for (int i = 0; i < 4; ++i)
#pragma unroll
        for (int j = 0; j < 2; ++j) acc[i][j] = zero4;

    // ---- reg-staging geometry ----
    // A tile 128x64 bf16: unit u = c*256+tid (c<4): row = c*32 + (tid>>3),
    //   slot s = tid&7. LDS 16B-unit = row*8 + (s ^ (row&7)) (XOR swizzle).
    // B tile 64x64 (f32 -> bf16): same mapping, c<2, two float4 loads per unit.
    int r0 = tid >> 3, s0 = tid & 7;
    const unsigned short* gA0 = &W1b[(size_t)(m0 + r0) * NFEAT + s0 * 8];
    const unsigned short* gA1 = gA0 + 32 * NFEAT;
    const unsigned short* gA2 = gA0 + 64 * NFEAT;
    const unsigned short* gA3 = gA0 + 96 * NFEAT;
    const float* gB0 = &x[(size_t)(n0 + r0) * NFEAT + s0 * 8];
    const float* gB1 = gB0 + 32 * NFEAT;
    const int iw0 = r0 * 8 + (s0 ^ (r0 & 7));
    const int iw1 = iw0 + 256, iw2 = iw0 + 512, iw3 = iw0 + 768;

    // two named register sets (rule #20: no runtime-indexed arrays)
    bf16x8 A0a, A0b, A0c, A0d;  float4 B0a, B0b, B0c, B0d;
    bf16x8 A1a, A1b, A1c, A1d;  float4 B1a, B1b, B1c, B1d;
    bf16x8 af0[4], af1[4], bg0[2], bg1[2];

#define LOADS0(T) do { int kk = (T) * BK;                           \
        A0a = *(const bf16x8*)(gA0 + kk); A0b = *(const bf16x8*)(gA1 + kk); \
        A0c = *(const bf16x8*)(gA2 + kk); A0d = *(const bf16x8*)(gA3 + kk); \
        B0a = *(const float4*)(gB0 + kk); B0b = *(const float4*)(gB0 + kk + 4); \
        B0c = *(const float4*)(gB1 + kk); B0d = *(const float4*)(gB1 + kk + 4); } while (0)
#define LOADS1(T) do { int kk = (T) * BK;                           \
        A1a = *(const bf16x8*)(gA0 + kk); A1b = *(const bf16x8*)(gA1 + kk); \
        A1c = *(const bf16x8*)(gA2 + kk); A1d = *(const bf16x8*)(gA3 + kk); \
        B1a = *(const float4*)(gB0 + kk); B1b = *(const float4*)(gB0 + kk + 4); \
        B1c = *(const float4*)(gB1 + kk); B1d = *(const float4*)(gB1 + kk + 4); } while (0)

#define STORE0(BUF) do {                                            \
        bf16x8* dA = (bf16x8*)&ldsA[BUF][0];                        \
        dA[iw0] = A0a; dA[iw1] = A0b; dA[iw2] = A0c; dA[iw3] = A0d; \
        uint4* dB = (uint4*)&ldsB[BUF][0];                          \
        dB[iw0] = pk8(B0a, B0b); dB[iw1] = pk8(B0c, B0d); } while (0)
#define STORE1(BUF) do {                                            \
        bf16x8* dA = (bf16x8*)&ldsA[BUF][0];                        \
        dA[iw0] = A1a; dA[iw1] = A1b; dA[iw2] = A1c; dA[iw3] = A1d; \
        uint4* dB = (uint4*)&ldsB[BUF][0];                          \
        dB[iw0] = pk8(B1a, B1b); dB[iw1] = pk8(B1c, B1d); } while (0)

#define READF(BUF) do {                                             \
        const unsigned short* bA = ldsA[BUF];                       \
        const unsigned short* bB = ldsB[BUF];                       \
        _Pragma("unroll")                                           \
        for (int i = 0; i < 4; ++i) {                               \
            int rowa = wm * 64 + i * 16 + lr;                       \
            af0[i] = *(const bf16x8*)&bA[(rowa * 8 + ((lg)     ^ (rowa & 7))) * 8]; \
            af1[i] = *(const bf16x8*)&bA[(rowa * 8 + ((4 + lg) ^ (rowa & 7))) * 8]; \
        }                                                           \
        _Pragma("unroll")                                           \
        for (int j = 0; j < 2; ++j) {                               \
            int rowb = wn * 32 + j * 16 + lr;                       \
            bg0[j] = *(const bf16x8*)&bB[(rowb * 8 + ((lg)     ^ (rowb & 7))) * 8]; \
            bg1[j] = *(const bf16x8*)&bB[(rowb * 8 + ((4 + lg) ^ (rowb & 7))) * 8]; \
        }                                                           \
    } while (0)

#define MFMAS() do {                                                \
        _Pragma("unroll")                                           \
        for (int i = 0; i < 4; ++i)                                 \
            _Pragma("unroll")                                       \
            for (int j = 0; j < 2; ++j)                             \
                acc[i][j] = __builtin_amdgcn_mfma_f32_16x16x32_bf16(af0[i], bg0[j], acc[i][j], 0, 0, 0); \
        _Pragma("unroll")                                           \
        for (int i = 0; i < 4; ++i)                                 \
            _Pragma("unroll")                                       \
            for (int j = 0; j < 2; ++j)                             \
                acc[i][j] = __builtin_amdgcn_mfma_f32_16x16x32_bf16(af1[i], bg1[j], acc[i][j], 0, 0, 0); \
    } while (0)

#define LDSFENCE() asm volatile("s_waitcnt lgkmcnt(0)" ::: "memory")

    // prologue: tiles 0,1 -> regs; store tile 0 (set1 loads stay in flight)
    LOADS0(0);
    LOADS1(1);
    STORE0(0);            // compiler waits set0's vmcnt precisely
    LDSFENCE();
    __builtin_amdgcn_s_barrier();

    // steady state: 15 pairs cover tiles 0..29.
    // Pair invariant: buf0 = tile 2p ready; set1 = tile 2p+1 in flight.
#pragma unroll 1
    for (int p = 0; p < 15; ++p) {
        int e = 2 * p;
        // even: compute tile e (buf0); load e+2 -> set0; store e+1 -> buf1
        LOADS0(e + 2);
        STORE1(1);        // waits set1 only (set0 stays in flight)
        READF(0);
        MFMAS();
        LDSFENCE();
        __builtin_amdgcn_s_barrier();
        // odd: compute tile e+1 (buf1); load e+3 -> set1; store e+2 -> buf0
        LOADS1(e + 3);
        STORE0(0);        // waits set0 only
        READF(1);
        MFMAS();
        LDSFENCE();
        __builtin_amdgcn_s_barrier();
    }
    // tail: buf0 = tile 30 ready; set1 = tile 31 in flight
    STORE1(1);
    READF(0);
    MFMAS();
    LDSFENCE();
    __builtin_amdgcn_s_barrier();
    READF(1);
    MFMAS();

#undef LOADS0
#undef LOADS1
#undef STORE0
#undef STORE1
#undef READF
#undef MFMAS
#undef LDSFENCE

    // ---- fused epilogue: h = sigmoid(acc + b1); pt[j][t] = sum_m h*W2d[m][t]
    // C/D layout: col(n) = lane&15, row(m) = (lane>>4)*4 + reg  [m89-verified]
    float pt[2][NTGT];
#pragma unroll
    for (int j = 0; j < 2; ++j)
#pragma unroll
        for (int t = 0; t < NTGT; ++t) pt[j][t] = 0.f;

#pragma unroll
    for (int i = 0; i < 4; ++i) {
#pragma unroll
        for (int r = 0; r < 4; ++r) {
            int ml = wm * 64 + i * 16 + lg * 4 + r;
            float bn = s_b1[ml];
#pragma unroll
            for (int j = 0; j < 2; ++j) {
                float h = 1.f / (1.f + __expf(-(acc[i][j][r] + bn)));
#pragma unroll
                for (int t = 0; t < NTGT; ++t)
                    pt[j][t] += h * s_w2[ml][t];
            }
        }
    }
    // reduce over lg (lanes lr+16*lg share the same n column)
#pragma unroll
    for (int j = 0; j < 2; ++j)
#pragma unroll
        for (int t = 0; t < NTGT; ++t) {
            float val = pt[j][t];
            val += __shfl_xor(val, 16, 64);
            val += __shfl_xor(val, 32, 64);
            pt[j][t] = val;
        }
    if (lg == 0) {
#pragma unroll
        for (int j = 0; j < 2; ++j) {
            int nl = wn * 32 + j * 16 + lr;
#pragma unroll
            for (int t = 0; t < NTGT; ++t)
                s_pt[wm][nl][t] = pt[j][t];
        }
    }
    __syncthreads();
    // atomic add 64 n x 8 t into out (pre-filled with b2); coalesced by tid
    for (int idx = tid; idx < BN * NTGT; idx += 256) {
        int nl = idx >> 3, t = idx & 7;
        atomicAdd(&out[(size_t)(n0 + nl) * NTGT + t], s_pt[0][nl][t] + s_pt[1][nl][t]);
    }
}

extern "C" void kernel_launch(void* const* d_in, const int* in_sizes, int n_in,
                              void* d_out, int out_size, void* d_ws, size_t ws_size,
                              hipStream_t stream) {
    (void)in_sizes; (void)n_in; (void)out_size; (void)ws_size;
    const float* x   = (const float*)d_in[0];
    const float* w1  = (const float*)d_in[1];
    const float* b1  = (const float*)d_in[2];
    const float* w2  = (const float*)d_in[3];
    const float* b2  = (const float*)d_in[4];
    const int*   c1o = (const int*)d_in[5];
    const int*   c1i = (const int*)d_in[6];
    const int*   c2o = (const int*)d_in[7];
    const int*   c2i = (const int*)d_in[8];
    float* out = (float*)d_out;

    char* ws = (char*)d_ws;
    float*          W1f  = (float*)(ws + OFF_W1F);
    float*          W2d  = (float*)(ws + OFF_W2D);
    unsigned short* W1b  = (unsigned short*)(ws + OFF_W1B);

    // zero W1f+W2d, pre-fill out with b2
    k_zero<<<(ZERO_FLOAT4 + OUT_FLOAT4 + 255) / 256, 256, 0, stream>>>(
        (float4*)ws, (float4*)out, b2);

    // dense weight build
    k_build<<<(NNZ1 + NNZ2) / 256, 256, 0, stream>>>(w1, c1o, c1i, w2, c2o, c2i, W1f, W2d);

    // fp32 -> bf16 for W1 only (x converted in-register inside k_gemm)
    k_convert<<<NNEUR * NFEAT / 4 / 256, 256, 0, stream>>>(W1f, W1b);

    // layer 1 GEMM + bias + sigmoid + layer-2 (atomic) all fused
    k_gemm<<<(NNEUR / BM) * (BATCH / BN), 256, 0, stream>>>(W1b, x, b1, W2d, out);
}